// Round 2
// baseline (26981.403 us; speedup 1.0000x reference)
//
#include <hip/hip_runtime.h>
#include <math.h>

#define B_TOK 128
#define HDIM  2048
#define NEXP  64
#define IDIM  768
#define TOPK  8
#define T32   32     // token tile
#define XK    128    // k-chunk (floats) staged in LDS

struct WS {
  int   counts[NEXP];
  int   tok_pair[NEXP][B_TOK];   // pair id = b*TOPK + slot
  float tok_wt[NEXP][B_TOK];     // renormalized routing weight
  float inter[B_TOK * TOPK][IDIM];
  float out_slots[B_TOK * TOPK][HDIM];
};

// ---------------------------------------------------------------- gating ----
__global__ __launch_bounds__(256) void gate_kernel(const float* __restrict__ x,
                                                   const float* __restrict__ gw,
                                                   WS* __restrict__ ws) {
  const int b    = blockIdx.x;
  const int e    = threadIdx.x & 63;
  const int part = threadIdx.x >> 6;
  const float* xr = x + (size_t)b * HDIM;
  const float* gr = gw + (size_t)e * HDIM;
  float acc = 0.f;
  const int h0 = part * (HDIM / 4);
  for (int h = h0; h < h0 + HDIM / 4; h += 4) {
    float4 xv = *(const float4*)(xr + h);
    float4 gv = *(const float4*)(gr + h);
    acc += xv.x * gv.x + xv.y * gv.y + xv.z * gv.z + xv.w * gv.w;
  }
  __shared__ float partial[4][NEXP];
  partial[part][e] = acc;
  __syncthreads();
  if (threadIdx.x < NEXP) {
    partial[0][e] = partial[0][e] + partial[1][e] + partial[2][e] + partial[3][e];
  }
  __syncthreads();
  if (threadIdx.x == 0) {
    float* logits = partial[0];
    unsigned long long mask = 0;
    int   idx[TOPK];
    float val[TOPK];
    for (int s = 0; s < TOPK; ++s) {
      float best = -3.4e38f; int bi = 0;
      for (int j = 0; j < NEXP; ++j) {
        if (!((mask >> j) & 1ull) && logits[j] > best) { best = logits[j]; bi = j; }
      }
      mask |= 1ull << bi; idx[s] = bi; val[s] = best;
    }
    float mx = val[0], denom = 0.f, w[TOPK];
    for (int s = 0; s < TOPK; ++s) { w[s] = expf(val[s] - mx); denom += w[s]; }
    float inv = 1.f / denom;
    for (int s = 0; s < TOPK; ++s) {
      int ee  = idx[s];
      int pos = atomicAdd(&ws->counts[ee], 1);
      ws->tok_pair[ee][pos] = b * TOPK + s;
      ws->tok_wt[ee][pos]   = w[s] * inv;
    }
  }
}

// --------------------------------------------------------------- ffn1 -------
// block = (expert e, 64-wide i-chunk). 256 threads = 128 rows (64 gate + 64 up)
// x 2-way K-split. Weights stream global->reg->FMA (no barrier in w path).
__global__ __launch_bounds__(256, 4) void ffn1_kernel(const float* __restrict__ x,
                                                      const float* __restrict__ w1,
                                                      WS* __restrict__ ws) {
  const int e  = blockIdx.x;
  const int i0 = blockIdx.y * 64;
  const int nt = ws->counts[e];
  if (nt == 0) return;

  __shared__ float sm[2 * 128 * 33];          // union: xs[32][128] | red[2][128][33]
  float (*xs)[XK] = (float (*)[XK])sm;
  __shared__ int spair[T32];

  const int tid = threadIdx.x;
  const int rs  = tid & 127;                  // row slot: <64 gate, >=64 up
  const int ks  = tid >> 7;                   // K-split half
  const int row = (rs < 64) ? (i0 + rs) : (IDIM + i0 + (rs - 64));
  const float* wrow = w1 + ((size_t)e * (2 * IDIM) + row) * HDIM + ks * 4;
  const int st = tid >> 3;                    // staging token
  const int sq = tid & 7;                     // staging 16-float slice

  for (int t0 = 0; t0 < nt; t0 += T32) {
    const int ntc   = min(T32, nt - t0);
    const int ntsub = (ntc + 7) >> 3;
    if (tid < T32) {
      int t = t0 + tid;
      spair[tid] = (t < nt) ? ws->tok_pair[e][t] : -1;
    }
    __syncthreads();
    const int pst = spair[st];
    const float* xsrc = x + (size_t)((st < ntc) ? (pst >> 3) : 0) * HDIM + sq * 16;

    float acc[T32];
#pragma unroll
    for (int i = 0; i < T32; ++i) acc[i] = 0.f;

    float4 p0, p1, p2, p3;
    { const float* s = xsrc;
      p0 = *(const float4*)s;       p1 = *(const float4*)(s + 4);
      p2 = *(const float4*)(s + 8); p3 = *(const float4*)(s + 12); }

    const int NC = HDIM / XK;   // 16
    for (int c = 0; c < NC; ++c) {
      { float* d = &xs[st][sq * 16];
        *(float4*)d = p0; *(float4*)(d + 4) = p1;
        *(float4*)(d + 8) = p2; *(float4*)(d + 12) = p3; }
      __syncthreads();
      if (c + 1 < NC) {            // prefetch next chunk; hidden under compute
        const float* s = xsrc + (c + 1) * XK;
        p0 = *(const float4*)s;       p1 = *(const float4*)(s + 4);
        p2 = *(const float4*)(s + 8); p3 = *(const float4*)(s + 12);
      }
      const float* wp = wrow + c * XK;
#pragma unroll 4
      for (int j = 0; j < XK / 8; ++j) {
        const float4 w4 = *(const float4*)(wp + j * 8);
        const int jk = j * 8 + ks * 4;
#pragma unroll
        for (int ts = 0; ts < 4; ++ts) {
          if (ts < ntsub) {
#pragma unroll
            for (int tt = 0; tt < 8; ++tt) {
              const float4 xv = *(const float4*)&xs[ts * 8 + tt][jk];
              acc[ts * 8 + tt] += w4.x * xv.x + w4.y * xv.y + w4.z * xv.z + w4.w * xv.w;
            }
          }
        }
      }
      __syncthreads();
    }

    // K-split reduce + silu epilogue (stride-33 LDS: conflict-free)
#pragma unroll
    for (int t = 0; t < T32; ++t) sm[(ks * 128 + rs) * 33 + t] = acc[t];
    __syncthreads();
    if (tid < 64) {
      for (int t = 0; t < ntc; ++t) {
        float g = sm[tid * 33 + t] + sm[(128 + tid) * 33 + t];
        float u = sm[(64 + tid) * 33 + t] + sm[(192 + tid) * 33 + t];
        float sv = g / (1.f + __expf(-g));
        ws->inter[spair[t]][i0 + tid] = sv * u;
      }
    }
    __syncthreads();
  }
}

// --------------------------------------------------------------- ffn2 -------
// block = (expert e, 128-wide h-chunk). 256 threads = 128 h-rows x 2-way K-split.
__global__ __launch_bounds__(256, 4) void ffn2_kernel(const float* __restrict__ w2,
                                                      WS* __restrict__ ws) {
  const int e  = blockIdx.x;
  const int h0 = blockIdx.y * 128;
  const int nt = ws->counts[e];
  if (nt == 0) return;

  __shared__ float sm[2 * 128 * 33];
  float (*xs)[XK] = (float (*)[XK])sm;
  __shared__ int   spair[T32];
  __shared__ float swt[T32];

  const int tid = threadIdx.x;
  const int rs  = tid & 127;
  const int ks  = tid >> 7;
  const float* wrow = w2 + ((size_t)e * HDIM + h0 + rs) * IDIM + ks * 4;
  const int st = tid >> 3;
  const int sq = tid & 7;

  for (int t0 = 0; t0 < nt; t0 += T32) {
    const int ntc   = min(T32, nt - t0);
    const int ntsub = (ntc + 7) >> 3;
    if (tid < T32) {
      int t = t0 + tid;
      spair[tid] = (t < nt) ? ws->tok_pair[e][t] : -1;
      swt[tid]   = (t < nt) ? ws->tok_wt[e][t] : 0.f;
    }
    __syncthreads();
    const int pst = spair[st];
    const float* xsrc = &ws->inter[(st < ntc) ? pst : 0][0] + sq * 16;

    float acc[T32];
#pragma unroll
    for (int i = 0; i < T32; ++i) acc[i] = 0.f;

    float4 p0, p1, p2, p3;
    { const float* s = xsrc;
      p0 = *(const float4*)s;       p1 = *(const float4*)(s + 4);
      p2 = *(const float4*)(s + 8); p3 = *(const float4*)(s + 12); }

    const int NC = IDIM / XK;   // 6
    for (int c = 0; c < NC; ++c) {
      { float* d = &xs[st][sq * 16];
        *(float4*)d = p0; *(float4*)(d + 4) = p1;
        *(float4*)(d + 8) = p2; *(float4*)(d + 12) = p3; }
      __syncthreads();
      if (c + 1 < NC) {
        const float* s = xsrc + (c + 1) * XK;
        p0 = *(const float4*)s;       p1 = *(const float4*)(s + 4);
        p2 = *(const float4*)(s + 8); p3 = *(const float4*)(s + 12);
      }
      const float* wp = wrow + c * XK;
#pragma unroll 4
      for (int j = 0; j < XK / 8; ++j) {
        const float4 w4 = *(const float4*)(wp + j * 8);
        const int jk = j * 8 + ks * 4;
#pragma unroll
        for (int ts = 0; ts < 4; ++ts) {
          if (ts < ntsub) {
#pragma unroll
            for (int tt = 0; tt < 8; ++tt) {
              const float4 xv = *(const float4*)&xs[ts * 8 + tt][jk];
              acc[ts * 8 + tt] += w4.x * xv.x + w4.y * xv.y + w4.z * xv.z + w4.w * xv.w;
            }
          }
        }
      }
      __syncthreads();
    }

#pragma unroll
    for (int t = 0; t < T32; ++t) sm[(ks * 128 + rs) * 33 + t] = acc[t];
    __syncthreads();
    if (tid < 128) {
      for (int t = 0; t < ntc; ++t) {
        float s = sm[tid * 33 + t] + sm[(128 + tid) * 33 + t];
        ws->out_slots[spair[t]][h0 + tid] = swt[t] * s;
      }
    }
    __syncthreads();
  }
}

// -------------------------------------------------------------- reduce ------
__global__ __launch_bounds__(256) void reduce_kernel(const WS* __restrict__ ws,
                                                     float* __restrict__ out) {
  int gid = blockIdx.x * 256 + threadIdx.x;
  int b   = gid >> 9;
  int h4  = (gid & 511) * 4;
  float4 s = {0, 0, 0, 0};
#pragma unroll
  for (int sl = 0; sl < TOPK; ++sl) {
    float4 v = *(const float4*)&ws->out_slots[b * TOPK + sl][h4];
    s.x += v.x; s.y += v.y; s.z += v.z; s.w += v.w;
  }
  *(float4*)(out + (size_t)b * HDIM + h4) = s;
}

// -------------------------------------------------------------- launch ------
extern "C" void kernel_launch(void* const* d_in, const int* in_sizes, int n_in,
                              void* d_out, int out_size, void* d_ws, size_t ws_size,
                              hipStream_t stream) {
  (void)in_sizes; (void)n_in; (void)out_size; (void)ws_size;
  const float* x  = (const float*)d_in[0];
  const float* gw = (const float*)d_in[1];
  const float* w1 = (const float*)d_in[2];
  const float* w2 = (const float*)d_in[3];
  WS* ws = (WS*)d_ws;

  hipMemsetAsync(ws->counts, 0, sizeof(int) * NEXP, stream);
  gate_kernel<<<B_TOK, 256, 0, stream>>>(x, gw, ws);
  ffn1_kernel<<<dim3(NEXP, IDIM / 64), 256, 0, stream>>>(x, w1, ws);
  ffn2_kernel<<<dim3(NEXP, HDIM / 128), 256, 0, stream>>>(w2, ws);
  reduce_kernel<<<(B_TOK * HDIM / 4) / 256, 256, 0, stream>>>(ws, (float*)d_out);
}